// Round 1
// baseline (1347.550 us; speedup 1.0000x reference)
//
#include <hip/hip_runtime.h>
#include <hip/hip_bf16.h>
#include <math.h>

#define HIDDEN 4096
#define HALF   2048
#define NE     64
#define TOPK   8

typedef __attribute__((ext_vector_type(8))) short          short8;
typedef __attribute__((ext_vector_type(4))) float          floatx4;
typedef __attribute__((ext_vector_type(4))) unsigned short ushort4v;

// ---------- bf16 split helpers ------------------------------------------------
__device__ inline unsigned short bf16_rne(float v) {
    union { float f; unsigned u; } x; x.f = v;
    unsigned r = x.u + 0x7fffu + ((x.u >> 16) & 1u);
    return (unsigned short)(r >> 16);
}
__device__ inline float bf16_to_f(unsigned short b) {
    union { unsigned u; float f; } x; x.u = (unsigned)b << 16;
    return x.f;
}

// ---------- h storage precision helpers (fallback paths) ----------------------
__device__ inline void hstore(float* p, float v) { *p = v; }
__device__ inline void hstore(__hip_bfloat16* p, float v) { *p = __float2bfloat16(v); }
__device__ inline float hload(const float* p) { return *p; }
__device__ inline float hload(const __hip_bfloat16* p) { return __bfloat162float(*p); }

// ---------- async global->LDS, 16B per lane -----------------------------------
__device__ inline void gl2lds16(const void* g, void* l) {
    __builtin_amdgcn_global_load_lds(
        (const __attribute__((address_space(1))) void*)g,
        (__attribute__((address_space(3))) void*)l, 16, 0, 0);
}

// ---------------------------------------------------------------------------
// P1: split x[T*4096] fp32 -> xh, xl bf16 (4 elems/thread)
// ---------------------------------------------------------------------------
__global__ __launch_bounds__(256) void split_x_k(const float* __restrict__ x,
                                                 unsigned short* __restrict__ hi,
                                                 unsigned short* __restrict__ lo) {
    const size_t i = ((size_t)blockIdx.x * 256 + threadIdx.x) * 4;
    float4 v = *(const float4*)(x + i);
    const float vs[4] = {v.x, v.y, v.z, v.w};
    ushort4v h4, l4;
#pragma unroll
    for (int j = 0; j < 4; ++j) {
        unsigned short hb = bf16_rne(vs[j]);
        h4[j] = hb;
        l4[j] = bf16_rne(vs[j] - bf16_to_f(hb));
    }
    *(ushort4v*)(hi + i) = h4;
    *(ushort4v*)(lo + i) = l4;
}

// ---------------------------------------------------------------------------
// P2: src[K][N] fp32 row-major -> transposed hi/lo [N][K] bf16.
// K = src ROW count, N = src COLUMN count. Grid (K/64, N/64), 256 thr.
// W1: (HIDDEN, HALF) -> grid (HIDDEN/64, HALF/64), args K=HIDDEN, N=HALF.
// ---------------------------------------------------------------------------
__global__ __launch_bounds__(256) void split_wt_k(const float* __restrict__ src,
                                                  unsigned short* __restrict__ wh,
                                                  unsigned short* __restrict__ wl,
                                                  int K, int N) {
    __shared__ float tile[64][65];
    const int tid = threadIdx.x;
    const int bk = blockIdx.x * 64, bn = blockIdx.y * 64;
    const int c4 = (tid & 15) * 4, r = tid >> 4;   // r in 0..15
#pragma unroll
    for (int rr = 0; rr < 4; ++rr) {
        const int row = r + rr * 16;
        *(float4*)&tile[row][c4] = *(const float4*)&src[(size_t)(bk + row) * N + bn + c4];
    }
    __syncthreads();
#pragma unroll
    for (int rr = 0; rr < 4; ++rr) {
        const int n = r + rr * 16;
        ushort4v h4, l4;
#pragma unroll
        for (int j = 0; j < 4; ++j) {
            float v = tile[c4 + j][n];
            unsigned short hb = bf16_rne(v);
            h4[j] = hb;
            l4[j] = bf16_rne(v - bf16_to_f(hb));
        }
        *(ushort4v*)&wh[(size_t)(bn + n) * K + bk + c4] = h4;
        *(ushort4v*)&wl[(size_t)(bn + n) * K + bk + c4] = l4;
    }
}

// ---------------------------------------------------------------------------
// K1 (pre-split): h = gelu_exact(x @ W1 + b1), 3-pass split-bf16 MFMA.
// MFMA/epilogue arithmetic BIT-IDENTICAL to the round-3/6 passing kernels.
// Decode: 1D grid 2048; c=id>>9 (m-chunk of 32 m-tiles), j=id&511,
// mt=c*32+(j>>4), nt=j&15. Per chunk: x window = 67 MB (LLC-resident),
// XCD k (=id%8 under round-robin) keeps nt in {k,k+8} (4 MB B, L2-resident).
//
// LDS bank-conflict fix (this round): the [128][32]-short tiles have a 64B
// row stride, so the fragment read (short8 at [row][q*8]) put each 8-lane
// LDS phase on only 2 of 8 16B granules -> 4-way conflict (6.7e7 conflict
// cycles/dispatch). Swizzle: physical = logical ^ ((row&7)<<4). Granule walk
// for rows 0..7 at fixed slot = {0,5,2,7,4,1,6,3} -> all 32 banks per phase.
// global_load_lds writes linearly, so the swizzle is applied by INVERSE-
// permuting the per-lane GLOBAL source address (rule 21: linear dest +
// inverse-swz source + swz read). Data values identical -> bit-identical out.
// ---------------------------------------------------------------------------
__global__ __launch_bounds__(256, 2) void gemm1_gelu_pre(const unsigned short* __restrict__ xh,
                                                         const unsigned short* __restrict__ xl,
                                                         const unsigned short* __restrict__ wh,
                                                         const unsigned short* __restrict__ wl,
                                                         const float* __restrict__ bias1,
                                                         float* __restrict__ h) {
    __shared__ unsigned short Ah[128][32];
    __shared__ unsigned short Al[128][32];
    __shared__ unsigned short Bh[128][32];
    __shared__ unsigned short Bl[128][32];

    const int tid = threadIdx.x;
    const int id  = blockIdx.x;
    const int c   = id >> 9;            // m-chunk 0..3
    const int j   = id & 511;
    const int m0  = ((c << 5) | (j >> 4)) * 128;   // mt in [c*32, c*32+32)
    const int N0  = (j & 15) * 128;                // nt 0..15, XCD = nt&7

    const int wave = tid >> 6, lane = tid & 63;
    const int wm   = (wave & 1) * 64;
    const int wn   = (wave >> 1) * 64;
    const int l15  = lane & 15;
    const int q    = lane >> 4;

    // ---- staging: lane's gl2lds lands at physical chunk byte P = lane*16.
    // Fetch the logical element L = swz^{-1}(P):
    //   L4 = P4^P6^P8, L5 = P5^P7, L6 = P6^P8  (P bits 4..9 = lane bits 0..5)
    const int p0 = lane & 1, p1 = (lane >> 1) & 1, p2 = (lane >> 2) & 1;
    const int p3 = (lane >> 3) & 1, p4 = (lane >> 4) & 1, p5 = (lane >> 5) & 1;
    const int slot_log = (p0 ^ p2 ^ p4) | ((p1 ^ p3) << 1);          // 16B slot 0..3
    const int row_log  = (p2 ^ p4) | (p3 << 1) | (p4 << 2) | (p5 << 3); // row 0..15

    const size_t lrow = (size_t)row_log;
    const int    lcol = slot_log * 8;
    const unsigned short* gp;
    unsigned short* lp;
    if (wave == 0)      { gp = xh + (m0 + lrow) * HIDDEN + lcol; lp = &Ah[0][0]; }
    else if (wave == 1) { gp = xl + (m0 + lrow) * HIDDEN + lcol; lp = &Al[0][0]; }
    else if (wave == 2) { gp = wh + (N0 + lrow) * HIDDEN + lcol; lp = &Bh[0][0]; }
    else                { gp = wl + (N0 + lrow) * HIDDEN + lcol; lp = &Bl[0][0]; }

    // ---- reader: forward swizzle folded into loop-invariant base offsets.
    // row = wm/wn + t*16 + l15 -> (row&7) == (l15&7); XOR touches bits 4-6
    // only, disjoint from t*1024, so it commutes with the t-step add.
    const unsigned sw   = ((unsigned)(l15 & 7)) << 4;
    const unsigned aoff = ((((unsigned)(wm + l15)) << 6) + ((unsigned)q << 4)) ^ sw;
    const unsigned boff = ((((unsigned)(wn + l15)) << 6) + ((unsigned)q << 4)) ^ sw;
    const char* AhB = (const char*)&Ah[0][0];
    const char* AlB = (const char*)&Al[0][0];
    const char* BhB = (const char*)&Bh[0][0];
    const char* BlB = (const char*)&Bl[0][0];

    floatx4 acc[4][4];
#pragma unroll
    for (int i = 0; i < 4; ++i)
#pragma unroll
        for (int jj = 0; jj < 4; ++jj) acc[i][jj] = (floatx4)0.f;

    for (int k0 = 0; k0 < HIDDEN; k0 += 32) {
        __syncthreads();
#pragma unroll
        for (int s = 0; s < 8; ++s)
            gl2lds16(gp + (size_t)s * 16 * HIDDEN, lp + s * 512);
        gp += 32;
        __syncthreads();

        short8 a_hi[4], a_lo[4], b_hi[4], b_lo[4];
#pragma unroll
        for (int t = 0; t < 4; ++t) {
            a_hi[t] = *(const short8*)(AhB + aoff + t * 1024);
            a_lo[t] = *(const short8*)(AlB + aoff + t * 1024);
            b_hi[t] = *(const short8*)(BhB + boff + t * 1024);
            b_lo[t] = *(const short8*)(BlB + boff + t * 1024);
        }
#pragma unroll
        for (int i = 0; i < 4; ++i)
#pragma unroll
            for (int jj = 0; jj < 4; ++jj) {
                acc[i][jj] = __builtin_amdgcn_mfma_f32_16x16x32_bf16(a_hi[i], b_hi[jj], acc[i][jj], 0, 0, 0);
                acc[i][jj] = __builtin_amdgcn_mfma_f32_16x16x32_bf16(a_lo[i], b_hi[jj], acc[i][jj], 0, 0, 0);
                acc[i][jj] = __builtin_amdgcn_mfma_f32_16x16x32_bf16(a_hi[i], b_lo[jj], acc[i][jj], 0, 0, 0);
            }
    }

    // epilogue: +bias, exact GELU, fp32 h (bit-identical to round-3/6).
#pragma unroll
    for (int jj = 0; jj < 4; ++jj) {
        const int n = N0 + wn + jj * 16 + l15;
        const float bb = bias1[n];
#pragma unroll
        for (int i = 0; i < 4; ++i) {
            const int mbase = m0 + wm + i * 16 + q * 4;
#pragma unroll
            for (int r = 0; r < 4; ++r) {
                float v = acc[i][jj][r] + bb;
                float g = 0.5f * v * (1.0f + erff(v * 0.70710678118654752f));
                h[(size_t)(mbase + r) * HALF + n] = g;
            }
        }
    }
}

// ---------------------------------------------------------------------------
// K2+K3 fused: logits = h @ W2 + b2 (4 tokens/block, bit-identical per-token
// fmaf chain: thread (e,q) sums k = q*512..q*512+511 ascending, then
// ((r0+r1)+(r2+r3))+b2) followed by in-block top-8 softmax + masked scatter.
// Wave w handles token r0+w; lane = expert. No logits round-trip.
// ---------------------------------------------------------------------------
template <typename HT>
__global__ __launch_bounds__(256) void gemm2_topk(const HT* __restrict__ h,
                                                  const float* __restrict__ W2,
                                                  const float* __restrict__ bias2,
                                                  const float* __restrict__ amask,
                                                  float* __restrict__ out, int T) {
    __shared__ float hs[4][HALF];          // 32 KB
    __shared__ float red[4][4][NE];        // [q][t][e], 4 KB
    const int tid = threadIdx.x;
    const size_t r0 = (size_t)blockIdx.x * 4;

    // stage 4 h rows (flat 8192 floats, coalesced)
    float* hsf = &hs[0][0];
    const HT* hr = h + r0 * HALF;
#pragma unroll
    for (int it = 0; it < 8; ++it) {
        const int i = tid * 4 + it * 1024;
        hsf[i + 0] = hload(hr + i + 0);
        hsf[i + 1] = hload(hr + i + 1);
        hsf[i + 2] = hload(hr + i + 2);
        hsf[i + 3] = hload(hr + i + 3);
    }
    __syncthreads();

    const int e = tid & 63, qq = tid >> 6;
    float s0 = 0.f, s1 = 0.f, s2 = 0.f, s3 = 0.f;
    const float* w = W2 + e;
    const int kbeg = qq * 512;
    for (int k4 = kbeg; k4 < kbeg + 512; k4 += 4) {
        float4 h0 = *(const float4*)&hs[0][k4];
        float4 h1 = *(const float4*)&hs[1][k4];
        float4 h2 = *(const float4*)&hs[2][k4];
        float4 h3 = *(const float4*)&hs[3][k4];
        float wv;
        wv = w[(size_t)(k4 + 0) * NE];
        s0 = fmaf(h0.x, wv, s0); s1 = fmaf(h1.x, wv, s1); s2 = fmaf(h2.x, wv, s2); s3 = fmaf(h3.x, wv, s3);
        wv = w[(size_t)(k4 + 1) * NE];
        s0 = fmaf(h0.y, wv, s0); s1 = fmaf(h1.y, wv, s1); s2 = fmaf(h2.y, wv, s2); s3 = fmaf(h3.y, wv, s3);
        wv = w[(size_t)(k4 + 2) * NE];
        s0 = fmaf(h0.z, wv, s0); s1 = fmaf(h1.z, wv, s1); s2 = fmaf(h2.z, wv, s2); s3 = fmaf(h3.z, wv, s3);
        wv = w[(size_t)(k4 + 3) * NE];
        s0 = fmaf(h0.w, wv, s0); s1 = fmaf(h1.w, wv, s1); s2 = fmaf(h2.w, wv, s2); s3 = fmaf(h3.w, wv, s3);
    }
    red[qq][0][e] = s0;
    red[qq][1][e] = s1;
    red[qq][2][e] = s2;
    red[qq][3][e] = s3;
    __syncthreads();

    // ---- per-wave token: final reduce (same add tree), top-8 softmax, mask
    const int wave = tid >> 6, lane = tid & 63;
    const size_t r = r0 + wave;
    const float v = ((red[0][wave][lane] + red[1][wave][lane]) +
                     (red[2][wave][lane] + red[3][wave][lane])) + bias2[lane];
    const float mk = amask[r];

    out[(size_t)T * NE + r * NE + lane] = v * mk;   // router_logits

    bool  sel = false;
    float m0 = 0.f, Z = 0.f;
#pragma unroll
    for (int it = 0; it < TOPK; ++it) {
        float cand = sel ? -INFINITY : v;
        int   idx  = lane;
#pragma unroll
        for (int off = 32; off; off >>= 1) {
            float ov = __shfl_xor(cand, off, 64);
            int   oi = __shfl_xor(idx,  off, 64);
            if (ov > cand || (ov == cand && oi < idx)) { cand = ov; idx = oi; }
        }
        if (it == 0) m0 = cand;
        Z += expf(cand - m0);
        if (lane == idx) sel = true;
    }
    const float wgt = sel ? (expf(v - m0) / Z) : 0.f;
    out[r * NE + lane] = wgt * mk;
}

// ---------------------------------------------------------------------------
// Fallback K1 (round-2): in-kernel conversion, fp32/bf16 h.
// ---------------------------------------------------------------------------
template <typename HT>
__global__ __launch_bounds__(256, 2) void gemm1_gelu_mfma(const float* __restrict__ x,
                                                          const float* __restrict__ W1,
                                                          const float* __restrict__ bias1,
                                                          HT* __restrict__ h) {
    __shared__ unsigned short Ah[128][40];
    __shared__ unsigned short Al[128][40];
    __shared__ unsigned short Bh[128][40];
    __shared__ unsigned short Bl[128][40];

    const int tid  = threadIdx.x;
    const int m0   = blockIdx.x * 128;
    const int n0   = blockIdx.y * 128;
    const int wave = tid >> 6, lane = tid & 63;
    const int wm   = (wave & 1) * 64;
    const int wn   = (wave >> 1) * 64;
    const int l15  = lane & 15;
    const int q    = lane >> 4;
    const int sm = tid & 127;
    const int kh = (tid >> 7) * 16;

    floatx4 acc[4][4];
#pragma unroll
    for (int i = 0; i < 4; ++i)
#pragma unroll
        for (int j = 0; j < 4; ++j) acc[i][j] = (floatx4)0.f;

    const float* xp = x  + (size_t)(m0 + sm) * HIDDEN + kh;
    const float* wp = W1 + (size_t)kh * HALF + n0 + sm;

    for (int k0 = 0; k0 < HIDDEN; k0 += 32) {
        float4 av[4];
#pragma unroll
        for (int i = 0; i < 4; ++i) av[i] = *(const float4*)(xp + k0 + i * 4);
        float bv[16];
#pragma unroll
        for (int i = 0; i < 16; ++i) bv[i] = wp[(size_t)(k0 + i) * HALF];

        __syncthreads();
        {
            unsigned short hi[16], lo[16];
#pragma unroll
            for (int i = 0; i < 4; ++i) {
                const float vs[4] = {av[i].x, av[i].y, av[i].z, av[i].w};
#pragma unroll
                for (int j = 0; j < 4; ++j) {
                    float v = vs[j];
                    unsigned short hb = bf16_rne(v);
                    hi[i * 4 + j] = hb;
                    lo[i * 4 + j] = bf16_rne(v - bf16_to_f(hb));
                }
            }
            *(short8*)&Ah[sm][kh]     = *(const short8*)&hi[0];
            *(short8*)&Ah[sm][kh + 8] = *(const short8*)&hi[8];
            *(short8*)&Al[sm][kh]     = *(const short8*)&lo[0];
            *(short8*)&Al[sm][kh + 8] = *(const short8*)&lo[8];
        }
        {
            unsigned short hi[16], lo[16];
#pragma unroll
            for (int i = 0; i < 16; ++i) {
                float v = bv[i];
                unsigned short hb = bf16_rne(v);
                hi[i] = hb;
                lo[i] = bf16_rne(v - bf16_to_f(hb));
            }
            *(short8*)&Bh[sm][kh]     = *(const short8*)&hi[0];
            *(short8*)&Bh[sm][kh + 8] = *(const short8*)&hi[8];
            *(short8*)&Bl[sm][kh]     = *(const short8*)&lo[0];
            *(short8*)&Bl[sm][kh + 8] = *(const short8*)&lo[8];
        }
        __syncthreads();

        short8 a_hi[4], a_lo[4], b_hi[4], b_lo[4];
#pragma unroll
        for (int t = 0; t < 4; ++t) {
            a_hi[t] = *(const short8*)&Ah[wm + t * 16 + l15][q * 8];
            a_lo[t] = *(const short8*)&Al[wm + t * 16 + l15][q * 8];
            b_hi[t] = *(const short8*)&Bh[wn + t * 16 + l15][q * 8];
            b_lo[t] = *(const short8*)&Bl[wn + t * 16 + l15][q * 8];
        }
#pragma unroll
        for (int i = 0; i < 4; ++i)
#pragma unroll
            for (int j = 0; j < 4; ++j) {
                acc[i][j] = __builtin_amdgcn_mfma_f32_16x16x32_bf16(a_hi[i], b_hi[j], acc[i][j], 0, 0, 0);
                acc[i][j] = __builtin_amdgcn_mfma_f32_16x16x32_bf16(a_lo[i], b_hi[j], acc[i][j], 0, 0, 0);
                acc[i][j] = __builtin_amdgcn_mfma_f32_16x16x32_bf16(a_hi[i], b_lo[j], acc[i][j], 0, 0, 0);
            }
    }

#pragma unroll
    for (int j = 0; j < 4; ++j) {
        const int n = n0 + wn + j * 16 + l15;
        const float bb = bias1[n];
#pragma unroll
        for (int i = 0; i < 4; ++i) {
            const int mbase = m0 + wm + i * 16 + q * 4;
#pragma unroll
            for (int r = 0; r < 4; ++r) {
                float v = acc[i][j][r] + bb;
                float g = 0.5f * v * (1.0f + erff(v * 0.70710678118654752f));
                hstore(h + (size_t)(mbase + r) * HALF + n, g);
            }
        }
    }
}

// ---------------------------------------------------------------------------
extern "C" void kernel_launch(void* const* d_in, const int* in_sizes, int n_in,
                              void* d_out, int out_size, void* d_ws, size_t ws_size,
                              hipStream_t stream) {
    const float* x   = (const float*)d_in[0];
    const float* am  = (const float*)d_in[1];
    const float* W1  = (const float*)d_in[2];
    const float* b1  = (const float*)d_in[3];
    const float* W2  = (const float*)d_in[4];
    const float* b2  = (const float*)d_in[5];
    float* out = (float*)d_out;

    const int T = in_sizes[0] / HIDDEN;   // 16384

    const size_t h32_bytes     = (size_t)T * HALF * sizeof(float);    // 134 MB
    const size_t h16_bytes     = (size_t)T * HALF * 2;                // 67 MB
    const size_t xsplit_bytes  = (size_t)T * HIDDEN * 2;              // 134 MB each
    const size_t w1split_bytes = (size_t)HIDDEN * HALF * 2;           // 16.8 MB each
    const size_t need_new = h32_bytes + 2 * xsplit_bytes + 2 * w1split_bytes;

    if (ws_size >= need_new) {
        char* p = (char*)d_ws;
        float* h = (float*)p;                     p += h32_bytes;
        unsigned short* xhp = (unsigned short*)p; p += xsplit_bytes;
        unsigned short* xlp = (unsigned short*)p; p += xsplit_bytes;
        unsigned short* w1h = (unsigned short*)p; p += w1split_bytes;
        unsigned short* w1l = (unsigned short*)p;

        const size_t xN = (size_t)T * HIDDEN;
        hipLaunchKernelGGL(split_x_k, dim3(xN / (4 * 256)), dim3(256), 0, stream, x, xhp, xlp);
        hipLaunchKernelGGL(split_wt_k, dim3(HIDDEN / 64, HALF / 64), dim3(256), 0, stream,
                           W1, w1h, w1l, HIDDEN, HALF);
        hipLaunchKernelGGL(gemm1_gelu_pre, dim3((T / 128) * (HALF / 128)), dim3(256), 0, stream,
                           xhp, xlp, w1h, w1l, b1, h);
        hipLaunchKernelGGL((gemm2_topk<float>), dim3(T / 4), dim3(256), 0, stream,
                           h, W2, b2, am, out, T);
    } else if (ws_size >= h32_bytes) {
        float* h = (float*)d_ws;
        hipLaunchKernelGGL((gemm1_gelu_mfma<float>), dim3(T / 128, HALF / 128), dim3(256), 0, stream,
                           x, W1, b1, h);
        hipLaunchKernelGGL((gemm2_topk<float>), dim3(T / 4), dim3(256), 0, stream,
                           h, W2, b2, am, out, T);
    } else {
        __hip_bfloat16* h = (__hip_bfloat16*)d_ws;
        hipLaunchKernelGGL((gemm1_gelu_mfma<__hip_bfloat16>), dim3(T / 128, HALF / 128), dim3(256), 0, stream,
                           x, W1, b1, h);
        hipLaunchKernelGGL((gemm2_topk<__hip_bfloat16>), dim3(T / 4), dim3(256), 0, stream,
                           h, W2, b2, am, out, T);
    }
}

// Round 2
// 1325.370 us; speedup vs baseline: 1.0167x; 1.0167x over previous
//
#include <hip/hip_runtime.h>
#include <hip/hip_bf16.h>
#include <math.h>

#define HIDDEN 4096
#define HALF   2048
#define NE     64
#define TOPK   8

typedef __attribute__((ext_vector_type(8))) short          short8;
typedef __attribute__((ext_vector_type(4))) float          floatx4;
typedef __attribute__((ext_vector_type(4))) unsigned short ushort4v;

// ---------- bf16 split helpers ------------------------------------------------
__device__ inline unsigned short bf16_rne(float v) {
    union { float f; unsigned u; } x; x.f = v;
    unsigned r = x.u + 0x7fffu + ((x.u >> 16) & 1u);
    return (unsigned short)(r >> 16);
}
__device__ inline float bf16_to_f(unsigned short b) {
    union { unsigned u; float f; } x; x.u = (unsigned)b << 16;
    return x.f;
}

// ---------- h storage precision helpers (fallback paths) ----------------------
__device__ inline void hstore(float* p, float v) { *p = v; }
__device__ inline void hstore(__hip_bfloat16* p, float v) { *p = __float2bfloat16(v); }
__device__ inline float hload(const float* p) { return *p; }
__device__ inline float hload(const __hip_bfloat16* p) { return __bfloat162float(*p); }

// ---------- async global->LDS, 16B per lane -----------------------------------
__device__ inline void gl2lds16(const void* g, void* l) {
    __builtin_amdgcn_global_load_lds(
        (const __attribute__((address_space(1))) void*)g,
        (__attribute__((address_space(3))) void*)l, 16, 0, 0);
}

// ---------------------------------------------------------------------------
// P1: split x[T*4096] fp32 -> xh, xl bf16 (4 elems/thread)
// ---------------------------------------------------------------------------
__global__ __launch_bounds__(256) void split_x_k(const float* __restrict__ x,
                                                 unsigned short* __restrict__ hi,
                                                 unsigned short* __restrict__ lo) {
    const size_t i = ((size_t)blockIdx.x * 256 + threadIdx.x) * 4;
    float4 v = *(const float4*)(x + i);
    const float vs[4] = {v.x, v.y, v.z, v.w};
    ushort4v h4, l4;
#pragma unroll
    for (int j = 0; j < 4; ++j) {
        unsigned short hb = bf16_rne(vs[j]);
        h4[j] = hb;
        l4[j] = bf16_rne(vs[j] - bf16_to_f(hb));
    }
    *(ushort4v*)(hi + i) = h4;
    *(ushort4v*)(lo + i) = l4;
}

// ---------------------------------------------------------------------------
// P2: src[K][N] fp32 row-major -> transposed hi/lo [N][K] bf16.
// K = src ROW count, N = src COLUMN count. Grid (K/64, N/64), 256 thr.
// W1: (HIDDEN, HALF) -> grid (HIDDEN/64, HALF/64), args K=HIDDEN, N=HALF.
// ---------------------------------------------------------------------------
__global__ __launch_bounds__(256) void split_wt_k(const float* __restrict__ src,
                                                  unsigned short* __restrict__ wh,
                                                  unsigned short* __restrict__ wl,
                                                  int K, int N) {
    __shared__ float tile[64][65];
    const int tid = threadIdx.x;
    const int bk = blockIdx.x * 64, bn = blockIdx.y * 64;
    const int c4 = (tid & 15) * 4, r = tid >> 4;   // r in 0..15
#pragma unroll
    for (int rr = 0; rr < 4; ++rr) {
        const int row = r + rr * 16;
        *(float4*)&tile[row][c4] = *(const float4*)&src[(size_t)(bk + row) * N + bn + c4];
    }
    __syncthreads();
#pragma unroll
    for (int rr = 0; rr < 4; ++rr) {
        const int n = r + rr * 16;
        ushort4v h4, l4;
#pragma unroll
        for (int j = 0; j < 4; ++j) {
            float v = tile[c4 + j][n];
            unsigned short hb = bf16_rne(v);
            h4[j] = hb;
            l4[j] = bf16_rne(v - bf16_to_f(hb));
        }
        *(ushort4v*)&wh[(size_t)(bn + n) * K + bk + c4] = h4;
        *(ushort4v*)&wl[(size_t)(bn + n) * K + bk + c4] = l4;
    }
}

// ---------------------------------------------------------------------------
// K1 (pre-split): h = gelu_exact(x @ W1 + b1), 3-pass split-bf16 MFMA.
// MFMA accumulation order per accumulator is BIT-IDENTICAL to the passing
// kernels (k ascending; hi*hi, lo*hi, hi*lo per 32-k step).
//
// Round-1 finding: SQ_LDS_BANK_CONFLICT = 4 cyc per ds_read_b128 in BOTH the
// linear and swizzled layouts (exactly 2^26 over 2^24 reads) — the 64 lanes
// cover a dense contiguous 1024B region, every bank hit exactly 8x, so the
// cost is intrinsic wave64-b128 phasing (m134: ~12 cyc), not a fixable
// conflict. Swizzle reverted.
//
// Round-2 change (T3+T4): double-buffered LDS + prefetch-next-kstep with a
// COUNTED s_waitcnt vmcnt(8) and raw s_barrier (no compiler vmcnt(0) drain),
// so the 8 gl2lds for kstep t+1 stay in flight under kstep t's ds_read+MFMA.
// vmcnt ledger: bias1 is preloaded+drained BEFORE the prologue so gl2lds are
// the only VMEM ops in flight inside the K-loop; 8 issued per kstep, in
// order, so vmcnt(8) == "buf[cur]'s 8 loads retired". asm memory clobbers
// bracket each raw barrier to pin IR-level load/store motion (m152 lesson).
// ---------------------------------------------------------------------------
__global__ __launch_bounds__(256, 2) void gemm1_gelu_pre(const unsigned short* __restrict__ xh,
                                                         const unsigned short* __restrict__ xl,
                                                         const unsigned short* __restrict__ wh,
                                                         const unsigned short* __restrict__ wl,
                                                         const float* __restrict__ bias1,
                                                         float* __restrict__ h) {
    __shared__ unsigned short Ah[2][128][32];   // 64 KB total: 2 blocks/CU
    __shared__ unsigned short Al[2][128][32];
    __shared__ unsigned short Bh[2][128][32];
    __shared__ unsigned short Bl[2][128][32];

    const int tid = threadIdx.x;
    const int id  = blockIdx.x;
    const int c   = id >> 9;            // m-chunk 0..3
    const int j   = id & 511;
    const int m0  = ((c << 5) | (j >> 4)) * 128;   // mt in [c*32, c*32+32)
    const int N0  = (j & 15) * 128;                // nt 0..15, XCD = nt&7

    const int wave = tid >> 6, lane = tid & 63;
    const int wm   = (wave & 1) * 64;
    const int wn   = (wave >> 1) * 64;
    const int l15  = lane & 15;
    const int q    = lane >> 4;

    const size_t lrow = (size_t)(lane >> 2);
    const int    lcol = (lane & 3) * 8;
    const unsigned short* gp;
    unsigned short* lp;
    if (wave == 0)      { gp = xh + (m0 + lrow) * HIDDEN + lcol; lp = &Ah[0][0][0]; }
    else if (wave == 1) { gp = xl + (m0 + lrow) * HIDDEN + lcol; lp = &Al[0][0][0]; }
    else if (wave == 2) { gp = wh + (N0 + lrow) * HIDDEN + lcol; lp = &Bh[0][0][0]; }
    else                { gp = wl + (N0 + lrow) * HIDDEN + lcol; lp = &Bl[0][0][0]; }

    // Preload epilogue bias into regs and drain, so the K-loop's vmcnt ledger
    // counts ONLY gl2lds ops.
    float bb[4];
#pragma unroll
    for (int jj = 0; jj < 4; ++jj) bb[jj] = bias1[N0 + wn + jj * 16 + l15];
    asm volatile("s_waitcnt vmcnt(0)" ::: "memory");

    // reader offsets (linear layout, loop-invariant; +cur*8192B selects buffer)
    const unsigned aoff = ((unsigned)(wm + l15)) * 64 + ((unsigned)q) * 16;
    const unsigned boff = ((unsigned)(wn + l15)) * 64 + ((unsigned)q) * 16;
    const char* AhB = (const char*)&Ah[0][0][0];
    const char* AlB = (const char*)&Al[0][0][0];
    const char* BhB = (const char*)&Bh[0][0][0];
    const char* BlB = (const char*)&Bl[0][0][0];

    floatx4 acc[4][4];
#pragma unroll
    for (int i = 0; i < 4; ++i)
#pragma unroll
        for (int jj = 0; jj < 4; ++jj) acc[i][jj] = (floatx4)0.f;

    // prologue: stage kstep 0 into buffer 0 (8 outstanding)
#pragma unroll
    for (int s = 0; s < 8; ++s)
        gl2lds16(gp + (size_t)s * 16 * HIDDEN, lp + s * 512);
    gp += 32;

    for (int t = 0; t < 128; ++t) {
        const int cur = t & 1;

        // B1: all waves retired their ds_reads of buf[cur^1] (kstep t-1),
        // so it is safe to overwrite it with kstep t+1's staging.
        asm volatile("" ::: "memory");
        __builtin_amdgcn_s_barrier();

        if (t < 127) {
            unsigned short* lq = lp + (cur ^ 1) * 4096;   // 128*32 shorts per tile
#pragma unroll
            for (int s = 0; s < 8; ++s)
                gl2lds16(gp + (size_t)s * 16 * HIDDEN, lq + s * 512);
            gp += 32;
            // wait for buf[cur]'s 8 loads (oldest); keep t+1's 8 in flight
            asm volatile("s_waitcnt vmcnt(8)" ::: "memory");
        } else {
            asm volatile("s_waitcnt vmcnt(0)" ::: "memory");
        }

        // B2: every wave has waited on its own staging -> all 4 tiles of
        // buf[cur] are visible to all waves.
        __builtin_amdgcn_s_barrier();
        asm volatile("" ::: "memory");

        const unsigned o = (unsigned)cur * 8192;
        short8 a_hi[4], a_lo[4], b_hi[4], b_lo[4];
#pragma unroll
        for (int tt = 0; tt < 4; ++tt) {
            a_hi[tt] = *(const short8*)(AhB + o + aoff + tt * 1024);
            a_lo[tt] = *(const short8*)(AlB + o + aoff + tt * 1024);
            b_hi[tt] = *(const short8*)(BhB + o + boff + tt * 1024);
            b_lo[tt] = *(const short8*)(BlB + o + boff + tt * 1024);
        }
#pragma unroll
        for (int i = 0; i < 4; ++i)
#pragma unroll
            for (int jj = 0; jj < 4; ++jj) {
                acc[i][jj] = __builtin_amdgcn_mfma_f32_16x16x32_bf16(a_hi[i], b_hi[jj], acc[i][jj], 0, 0, 0);
                acc[i][jj] = __builtin_amdgcn_mfma_f32_16x16x32_bf16(a_lo[i], b_hi[jj], acc[i][jj], 0, 0, 0);
                acc[i][jj] = __builtin_amdgcn_mfma_f32_16x16x32_bf16(a_hi[i], b_lo[jj], acc[i][jj], 0, 0, 0);
            }
    }

    // epilogue: +bias, exact GELU, fp32 h (bit-identical arithmetic).
#pragma unroll
    for (int jj = 0; jj < 4; ++jj) {
        const int n = N0 + wn + jj * 16 + l15;
#pragma unroll
        for (int i = 0; i < 4; ++i) {
            const int mbase = m0 + wm + i * 16 + q * 4;
#pragma unroll
            for (int r = 0; r < 4; ++r) {
                float v = acc[i][jj][r] + bb[jj];
                float g = 0.5f * v * (1.0f + erff(v * 0.70710678118654752f));
                h[(size_t)(mbase + r) * HALF + n] = g;
            }
        }
    }
}

// ---------------------------------------------------------------------------
// K2+K3 fused: logits = h @ W2 + b2 (4 tokens/block, bit-identical per-token
// fmaf chain: thread (e,q) sums k = q*512..q*512+511 ascending, then
// ((r0+r1)+(r2+r3))+b2) followed by in-block top-8 softmax + masked scatter.
// Wave w handles token r0+w; lane = expert. No logits round-trip.
// ---------------------------------------------------------------------------
template <typename HT>
__global__ __launch_bounds__(256) void gemm2_topk(const HT* __restrict__ h,
                                                  const float* __restrict__ W2,
                                                  const float* __restrict__ bias2,
                                                  const float* __restrict__ amask,
                                                  float* __restrict__ out, int T) {
    __shared__ float hs[4][HALF];          // 32 KB
    __shared__ float red[4][4][NE];        // [q][t][e], 4 KB
    const int tid = threadIdx.x;
    const size_t r0 = (size_t)blockIdx.x * 4;

    // stage 4 h rows (flat 8192 floats, coalesced)
    float* hsf = &hs[0][0];
    const HT* hr = h + r0 * HALF;
#pragma unroll
    for (int it = 0; it < 8; ++it) {
        const int i = tid * 4 + it * 1024;
        hsf[i + 0] = hload(hr + i + 0);
        hsf[i + 1] = hload(hr + i + 1);
        hsf[i + 2] = hload(hr + i + 2);
        hsf[i + 3] = hload(hr + i + 3);
    }
    __syncthreads();

    const int e = tid & 63, qq = tid >> 6;
    float s0 = 0.f, s1 = 0.f, s2 = 0.f, s3 = 0.f;
    const float* w = W2 + e;
    const int kbeg = qq * 512;
    for (int k4 = kbeg; k4 < kbeg + 512; k4 += 4) {
        float4 h0 = *(const float4*)&hs[0][k4];
        float4 h1 = *(const float4*)&hs[1][k4];
        float4 h2 = *(const float4*)&hs[2][k4];
        float4 h3 = *(const float4*)&hs[3][k4];
        float wv;
        wv = w[(size_t)(k4 + 0) * NE];
        s0 = fmaf(h0.x, wv, s0); s1 = fmaf(h1.x, wv, s1); s2 = fmaf(h2.x, wv, s2); s3 = fmaf(h3.x, wv, s3);
        wv = w[(size_t)(k4 + 1) * NE];
        s0 = fmaf(h0.y, wv, s0); s1 = fmaf(h1.y, wv, s1); s2 = fmaf(h2.y, wv, s2); s3 = fmaf(h3.y, wv, s3);
        wv = w[(size_t)(k4 + 2) * NE];
        s0 = fmaf(h0.z, wv, s0); s1 = fmaf(h1.z, wv, s1); s2 = fmaf(h2.z, wv, s2); s3 = fmaf(h3.z, wv, s3);
        wv = w[(size_t)(k4 + 3) * NE];
        s0 = fmaf(h0.w, wv, s0); s1 = fmaf(h1.w, wv, s1); s2 = fmaf(h2.w, wv, s2); s3 = fmaf(h3.w, wv, s3);
    }
    red[qq][0][e] = s0;
    red[qq][1][e] = s1;
    red[qq][2][e] = s2;
    red[qq][3][e] = s3;
    __syncthreads();

    // ---- per-wave token: final reduce (same add tree), top-8 softmax, mask
    const int wave = tid >> 6, lane = tid & 63;
    const size_t r = r0 + wave;
    const float v = ((red[0][wave][lane] + red[1][wave][lane]) +
                     (red[2][wave][lane] + red[3][wave][lane])) + bias2[lane];
    const float mk = amask[r];

    out[(size_t)T * NE + r * NE + lane] = v * mk;   // router_logits

    bool  sel = false;
    float m0 = 0.f, Z = 0.f;
#pragma unroll
    for (int it = 0; it < TOPK; ++it) {
        float cand = sel ? -INFINITY : v;
        int   idx  = lane;
#pragma unroll
        for (int off = 32; off; off >>= 1) {
            float ov = __shfl_xor(cand, off, 64);
            int   oi = __shfl_xor(idx,  off, 64);
            if (ov > cand || (ov == cand && oi < idx)) { cand = ov; idx = oi; }
        }
        if (it == 0) m0 = cand;
        Z += expf(cand - m0);
        if (lane == idx) sel = true;
    }
    const float wgt = sel ? (expf(v - m0) / Z) : 0.f;
    out[r * NE + lane] = wgt * mk;
}

// ---------------------------------------------------------------------------
// Fallback K1 (round-2): in-kernel conversion, fp32/bf16 h.
// ---------------------------------------------------------------------------
template <typename HT>
__global__ __launch_bounds__(256, 2) void gemm1_gelu_mfma(const float* __restrict__ x,
                                                          const float* __restrict__ W1,
                                                          const float* __restrict__ bias1,
                                                          HT* __restrict__ h) {
    __shared__ unsigned short Ah[128][40];
    __shared__ unsigned short Al[128][40];
    __shared__ unsigned short Bh[128][40];
    __shared__ unsigned short Bl[128][40];

    const int tid  = threadIdx.x;
    const int m0   = blockIdx.x * 128;
    const int n0   = blockIdx.y * 128;
    const int wave = tid >> 6, lane = tid & 63;
    const int wm   = (wave & 1) * 64;
    const int wn   = (wave >> 1) * 64;
    const int l15  = lane & 15;
    const int q    = lane >> 4;
    const int sm = tid & 127;
    const int kh = (tid >> 7) * 16;

    floatx4 acc[4][4];
#pragma unroll
    for (int i = 0; i < 4; ++i)
#pragma unroll
        for (int j = 0; j < 4; ++j) acc[i][j] = (floatx4)0.f;

    const float* xp = x  + (size_t)(m0 + sm) * HIDDEN + kh;
    const float* wp = W1 + (size_t)kh * HALF + n0 + sm;

    for (int k0 = 0; k0 < HIDDEN; k0 += 32) {
        float4 av[4];
#pragma unroll
        for (int i = 0; i < 4; ++i) av[i] = *(const float4*)(xp + k0 + i * 4);
        float bv[16];
#pragma unroll
        for (int i = 0; i < 16; ++i) bv[i] = wp[(size_t)(k0 + i) * HALF];

        __syncthreads();
        {
            unsigned short hi[16], lo[16];
#pragma unroll
            for (int i = 0; i < 4; ++i) {
                const float vs[4] = {av[i].x, av[i].y, av[i].z, av[i].w};
#pragma unroll
                for (int j = 0; j < 4; ++j) {
                    float v = vs[j];
                    unsigned short hb = bf16_rne(v);
                    hi[i * 4 + j] = hb;
                    lo[i * 4 + j] = bf16_rne(v - bf16_to_f(hb));
                }
            }
            *(short8*)&Ah[sm][kh]     = *(const short8*)&hi[0];
            *(short8*)&Ah[sm][kh + 8] = *(const short8*)&hi[8];
            *(short8*)&Al[sm][kh]     = *(const short8*)&lo[0];
            *(short8*)&Al[sm][kh + 8] = *(const short8*)&lo[8];
        }
        {
            unsigned short hi[16], lo[16];
#pragma unroll
            for (int i = 0; i < 16; ++i) {
                float v = bv[i];
                unsigned short hb = bf16_rne(v);
                hi[i] = hb;
                lo[i] = bf16_rne(v - bf16_to_f(hb));
            }
            *(short8*)&Bh[sm][kh]     = *(const short8*)&hi[0];
            *(short8*)&Bh[sm][kh + 8] = *(const short8*)&hi[8];
            *(short8*)&Bl[sm][kh]     = *(const short8*)&lo[0];
            *(short8*)&Bl[sm][kh + 8] = *(const short8*)&lo[8];
        }
        __syncthreads();

        short8 a_hi[4], a_lo[4], b_hi[4], b_lo[4];
#pragma unroll
        for (int t = 0; t < 4; ++t) {
            a_hi[t] = *(const short8*)&Ah[wm + t * 16 + l15][q * 8];
            a_lo[t] = *(const short8*)&Al[wm + t * 16 + l15][q * 8];
            b_hi[t] = *(const short8*)&Bh[wn + t * 16 + l15][q * 8];
            b_lo[t] = *(const short8*)&Bl[wn + t * 16 + l15][q * 8];
        }
#pragma unroll
        for (int i = 0; i < 4; ++i)
#pragma unroll
            for (int j = 0; j < 4; ++j) {
                acc[i][j] = __builtin_amdgcn_mfma_f32_16x16x32_bf16(a_hi[i], b_hi[j], acc[i][j], 0, 0, 0);
                acc[i][j] = __builtin_amdgcn_mfma_f32_16x16x32_bf16(a_lo[i], b_hi[j], acc[i][j], 0, 0, 0);
                acc[i][j] = __builtin_amdgcn_mfma_f32_16x16x32_bf16(a_hi[i], b_lo[j], acc[i][j], 0, 0, 0);
            }
    }

#pragma unroll
    for (int j = 0; j < 4; ++j) {
        const int n = n0 + wn + j * 16 + l15;
        const float bb = bias1[n];
#pragma unroll
        for (int i = 0; i < 4; ++i) {
            const int mbase = m0 + wm + i * 16 + q * 4;
#pragma unroll
            for (int r = 0; r < 4; ++r) {
                float v = acc[i][j][r] + bb;
                float g = 0.5f * v * (1.0f + erff(v * 0.70710678118654752f));
                hstore(h + (size_t)(mbase + r) * HALF + n, g);
            }
        }
    }
}

// ---------------------------------------------------------------------------
extern "C" void kernel_launch(void* const* d_in, const int* in_sizes, int n_in,
                              void* d_out, int out_size, void* d_ws, size_t ws_size,
                              hipStream_t stream) {
    const float* x   = (const float*)d_in[0];
    const float* am  = (const float*)d_in[1];
    const float* W1  = (const float*)d_in[2];
    const float* b1  = (const float*)d_in[3];
    const float* W2  = (const float*)d_in[4];
    const float* b2  = (const float*)d_in[5];
    float* out = (float*)d_out;

    const int T = in_sizes[0] / HIDDEN;   // 16384

    const size_t h32_bytes     = (size_t)T * HALF * sizeof(float);    // 134 MB
    const size_t h16_bytes     = (size_t)T * HALF * 2;                // 67 MB
    const size_t xsplit_bytes  = (size_t)T * HIDDEN * 2;              // 134 MB each
    const size_t w1split_bytes = (size_t)HIDDEN * HALF * 2;           // 16.8 MB each
    const size_t need_new = h32_bytes + 2 * xsplit_bytes + 2 * w1split_bytes;

    if (ws_size >= need_new) {
        char* p = (char*)d_ws;
        float* h = (float*)p;                     p += h32_bytes;
        unsigned short* xhp = (unsigned short*)p; p += xsplit_bytes;
        unsigned short* xlp = (unsigned short*)p; p += xsplit_bytes;
        unsigned short* w1h = (unsigned short*)p; p += w1split_bytes;
        unsigned short* w1l = (unsigned short*)p;

        const size_t xN = (size_t)T * HIDDEN;
        hipLaunchKernelGGL(split_x_k, dim3(xN / (4 * 256)), dim3(256), 0, stream, x, xhp, xlp);
        hipLaunchKernelGGL(split_wt_k, dim3(HIDDEN / 64, HALF / 64), dim3(256), 0, stream,
                           W1, w1h, w1l, HIDDEN, HALF);
        hipLaunchKernelGGL(gemm1_gelu_pre, dim3((T / 128) * (HALF / 128)), dim3(256), 0, stream,
                           xhp, xlp, w1h, w1l, b1, h);
        hipLaunchKernelGGL((gemm2_topk<float>), dim3(T / 4), dim3(256), 0, stream,
                           h, W2, b2, am, out, T);
    } else if (ws_size >= h32_bytes) {
        float* h = (float*)d_ws;
        hipLaunchKernelGGL((gemm1_gelu_mfma<float>), dim3(T / 128, HALF / 128), dim3(256), 0, stream,
                           x, W1, b1, h);
        hipLaunchKernelGGL((gemm2_topk<float>), dim3(T / 4), dim3(256), 0, stream,
                           h, W2, b2, am, out, T);
    } else {
        __hip_bfloat16* h = (__hip_bfloat16*)d_ws;
        hipLaunchKernelGGL((gemm1_gelu_mfma<__hip_bfloat16>), dim3(T / 128, HALF / 128), dim3(256), 0, stream,
                           x, W1, b1, h);
        hipLaunchKernelGGL((gemm2_topk<__hip_bfloat16>), dim3(T / 4), dim3(256), 0, stream,
                           h, W2, b2, am, out, T);
    }
}

// Round 3
// 1307.145 us; speedup vs baseline: 1.0309x; 1.0139x over previous
//
#include <hip/hip_runtime.h>
#include <hip/hip_bf16.h>
#include <math.h>

#define HIDDEN 4096
#define HALF   2048
#define NE     64
#define TOPK   8

typedef __attribute__((ext_vector_type(8))) short          short8;
typedef __attribute__((ext_vector_type(4))) float          floatx4;
typedef __attribute__((ext_vector_type(4))) unsigned short ushort4v;

// ---------- bf16 split helpers ------------------------------------------------
__device__ inline unsigned short bf16_rne(float v) {
    union { float f; unsigned u; } x; x.f = v;
    unsigned r = x.u + 0x7fffu + ((x.u >> 16) & 1u);
    return (unsigned short)(r >> 16);
}
__device__ inline float bf16_to_f(unsigned short b) {
    union { unsigned u; float f; } x; x.u = (unsigned)b << 16;
    return x.f;
}

// ---------- h storage precision helpers (fallback paths) ----------------------
__device__ inline void hstore(float* p, float v) { *p = v; }
__device__ inline void hstore(__hip_bfloat16* p, float v) { *p = __float2bfloat16(v); }
__device__ inline float hload(const float* p) { return *p; }
__device__ inline float hload(const __hip_bfloat16* p) { return __bfloat162float(*p); }

// ---------- async global->LDS, 16B per lane -----------------------------------
__device__ inline void gl2lds16(const void* g, void* l) {
    __builtin_amdgcn_global_load_lds(
        (const __attribute__((address_space(1))) void*)g,
        (__attribute__((address_space(3))) void*)l, 16, 0, 0);
}

// ---------------------------------------------------------------------------
// P1: split x[T*4096] fp32 -> xh, xl bf16 (4 elems/thread)
// ---------------------------------------------------------------------------
__global__ __launch_bounds__(256) void split_x_k(const float* __restrict__ x,
                                                 unsigned short* __restrict__ hi,
                                                 unsigned short* __restrict__ lo) {
    const size_t i = ((size_t)blockIdx.x * 256 + threadIdx.x) * 4;
    float4 v = *(const float4*)(x + i);
    const float vs[4] = {v.x, v.y, v.z, v.w};
    ushort4v h4, l4;
#pragma unroll
    for (int j = 0; j < 4; ++j) {
        unsigned short hb = bf16_rne(vs[j]);
        h4[j] = hb;
        l4[j] = bf16_rne(vs[j] - bf16_to_f(hb));
    }
    *(ushort4v*)(hi + i) = h4;
    *(ushort4v*)(lo + i) = l4;
}

// ---------------------------------------------------------------------------
// P2: src[K][N] fp32 row-major -> transposed hi/lo [N][K] bf16.
// ---------------------------------------------------------------------------
__global__ __launch_bounds__(256) void split_wt_k(const float* __restrict__ src,
                                                  unsigned short* __restrict__ wh,
                                                  unsigned short* __restrict__ wl,
                                                  int K, int N) {
    __shared__ float tile[64][65];
    const int tid = threadIdx.x;
    const int bk = blockIdx.x * 64, bn = blockIdx.y * 64;
    const int c4 = (tid & 15) * 4, r = tid >> 4;   // r in 0..15
#pragma unroll
    for (int rr = 0; rr < 4; ++rr) {
        const int row = r + rr * 16;
        *(float4*)&tile[row][c4] = *(const float4*)&src[(size_t)(bk + row) * N + bn + c4];
    }
    __syncthreads();
#pragma unroll
    for (int rr = 0; rr < 4; ++rr) {
        const int n = r + rr * 16;
        ushort4v h4, l4;
#pragma unroll
        for (int j = 0; j < 4; ++j) {
            float v = tile[c4 + j][n];
            unsigned short hb = bf16_rne(v);
            h4[j] = hb;
            l4[j] = bf16_rne(v - bf16_to_f(hb));
        }
        *(ushort4v*)&wh[(size_t)(bn + n) * K + bk + c4] = h4;
        *(ushort4v*)&wl[(size_t)(bn + n) * K + bk + c4] = l4;
    }
}

// ---------------------------------------------------------------------------
// K1 (pre-split): h = gelu_exact(x @ W1 + b1), 3-pass split-bf16 MFMA.
// Per-output accumulation chains are order-identical to all prior passing
// kernels (k ascending in steps of 32; hi*hi, lo*hi, hi*lo per step) ->
// bit-identical h regardless of tile geometry.
//
// Round-2 counters: MFMA pipes ~12% busy (raw count), LDS unit ~53%, HBM 29%
// -> latency/barrier-bound with LDS as the largest real pipe. Round-3 change:
// scale tile to 256x256 (512 thr, 8 waves 2m x 4n, per-wave 128x64 out).
// 4x work per kstep for ~3x LDS traffic and the SAME fixed per-kstep tax.
// Sync structure unchanged from the round-2 proven kernel: double-buffered
// LDS (128 KB), raw s_barrier pair, per-wave counted vmcnt(8) ledger
// (each wave issues exactly 8 gl2lds per kstep; bias preloaded+drained
// before the prologue so gl2lds are the only VMEM ops in flight).
// ---------------------------------------------------------------------------
__global__ __launch_bounds__(512, 2) void gemm1_gelu_pre(const unsigned short* __restrict__ xh,
                                                         const unsigned short* __restrict__ xl,
                                                         const unsigned short* __restrict__ wh,
                                                         const unsigned short* __restrict__ wl,
                                                         const float* __restrict__ bias1,
                                                         float* __restrict__ h) {
    __shared__ unsigned short Ah[2][256][32];   // 32 KB each array-pair, 128 KB total
    __shared__ unsigned short Al[2][256][32];
    __shared__ unsigned short Bh[2][256][32];
    __shared__ unsigned short Bl[2][256][32];

    const int tid = threadIdx.x;
    const int id  = blockIdx.x;          // 0..511
    const int m0  = (id >> 3) * 256;     // 64 m-tiles
    const int N0  = (id & 7) * 256;      // 8 n-tiles; XCD = id%8 affinity

    const int wave = tid >> 6, lane = tid & 63;
    const int wmi  = wave >> 2;          // 0..1  (m-wave)
    const int wni  = wave & 3;           // 0..3  (n-wave)
    const int l15  = lane & 15;
    const int q    = lane >> 4;

    // ---- staging role: arr = wave>>1 (0:Ah 1:Al 2:Bh 3:Bl), half = wave&1
    // (rows 0-127 / 128-255 of the 256-row tile). 8 gl2lds of 16 rows each.
    const size_t lrow = (size_t)(lane >> 2);
    const int    lcol = (lane & 3) * 8;
    const int    half = wave & 1;
    const int    arr  = wave >> 1;
    const unsigned short* gp;
    unsigned short* lp;
    if (arr == 0)      { gp = xh + (size_t)(m0 + half * 128 + lrow) * HIDDEN + lcol; lp = &Ah[0][half * 128][0]; }
    else if (arr == 1) { gp = xl + (size_t)(m0 + half * 128 + lrow) * HIDDEN + lcol; lp = &Al[0][half * 128][0]; }
    else if (arr == 2) { gp = wh + (size_t)(N0 + half * 128 + lrow) * HIDDEN + lcol; lp = &Bh[0][half * 128][0]; }
    else               { gp = wl + (size_t)(N0 + half * 128 + lrow) * HIDDEN + lcol; lp = &Bl[0][half * 128][0]; }

    // Preload epilogue bias into regs and drain, so the K-loop's vmcnt ledger
    // counts ONLY gl2lds ops.
    float bb[4];
#pragma unroll
    for (int jj = 0; jj < 4; ++jj) bb[jj] = bias1[N0 + wni * 64 + jj * 16 + l15];
    asm volatile("s_waitcnt vmcnt(0)" ::: "memory");

    // reader byte offsets (linear layout, loop-invariant; +cur*16384B = buffer)
    const unsigned aoff = ((unsigned)(wmi * 128 + l15)) * 64 + ((unsigned)q) * 16;
    const unsigned boff = ((unsigned)(wni * 64  + l15)) * 64 + ((unsigned)q) * 16;
    const char* AhB = (const char*)&Ah[0][0][0];
    const char* AlB = (const char*)&Al[0][0][0];
    const char* BhB = (const char*)&Bh[0][0][0];
    const char* BlB = (const char*)&Bl[0][0][0];

    floatx4 acc[8][4];
#pragma unroll
    for (int i = 0; i < 8; ++i)
#pragma unroll
        for (int jj = 0; jj < 4; ++jj) acc[i][jj] = (floatx4)0.f;

    // prologue: stage kstep 0 into buffer 0 (8 outstanding per wave)
#pragma unroll
    for (int s = 0; s < 8; ++s)
        gl2lds16(gp + (size_t)s * 16 * HIDDEN, lp + s * 512);
    gp += 32;

    for (int t = 0; t < 128; ++t) {
        const int cur = t & 1;

        // B1: all waves retired their ds_reads of buf[cur^1] (kstep t-1),
        // so it is safe to overwrite it with kstep t+1's staging.
        asm volatile("" ::: "memory");
        __builtin_amdgcn_s_barrier();

        if (t < 127) {
            unsigned short* lq = lp + (cur ^ 1) * 8192;   // 256*32 shorts per tile
#pragma unroll
            for (int s = 0; s < 8; ++s)
                gl2lds16(gp + (size_t)s * 16 * HIDDEN, lq + s * 512);
            gp += 32;
            // wait for buf[cur]'s 8 loads (oldest); keep t+1's 8 in flight
            asm volatile("s_waitcnt vmcnt(8)" ::: "memory");
        } else {
            asm volatile("s_waitcnt vmcnt(0)" ::: "memory");
        }

        // B2: every wave has waited on its own staging -> all 4 tiles of
        // buf[cur] visible to all waves.
        __builtin_amdgcn_s_barrier();
        asm volatile("" ::: "memory");

        const unsigned o = (unsigned)cur * 16384;
        short8 a_hi[8], a_lo[8], b_hi[4], b_lo[4];
#pragma unroll
        for (int i = 0; i < 8; ++i) {
            a_hi[i] = *(const short8*)(AhB + o + aoff + i * 1024);
            a_lo[i] = *(const short8*)(AlB + o + aoff + i * 1024);
        }
#pragma unroll
        for (int jj = 0; jj < 4; ++jj) {
            b_hi[jj] = *(const short8*)(BhB + o + boff + jj * 1024);
            b_lo[jj] = *(const short8*)(BlB + o + boff + jj * 1024);
        }
#pragma unroll
        for (int i = 0; i < 8; ++i)
#pragma unroll
            for (int jj = 0; jj < 4; ++jj) {
                acc[i][jj] = __builtin_amdgcn_mfma_f32_16x16x32_bf16(a_hi[i], b_hi[jj], acc[i][jj], 0, 0, 0);
                acc[i][jj] = __builtin_amdgcn_mfma_f32_16x16x32_bf16(a_lo[i], b_hi[jj], acc[i][jj], 0, 0, 0);
                acc[i][jj] = __builtin_amdgcn_mfma_f32_16x16x32_bf16(a_hi[i], b_lo[jj], acc[i][jj], 0, 0, 0);
            }
    }

    // epilogue: +bias, exact GELU, fp32 h (bit-identical arithmetic).
#pragma unroll
    for (int jj = 0; jj < 4; ++jj) {
        const int n = N0 + wni * 64 + jj * 16 + l15;
#pragma unroll
        for (int i = 0; i < 8; ++i) {
            const int mbase = m0 + wmi * 128 + i * 16 + q * 4;
#pragma unroll
            for (int r = 0; r < 4; ++r) {
                float v = acc[i][jj][r] + bb[jj];
                float g = 0.5f * v * (1.0f + erff(v * 0.70710678118654752f));
                h[(size_t)(mbase + r) * HALF + n] = g;
            }
        }
    }
}

// ---------------------------------------------------------------------------
// K2+K3 fused: logits = h @ W2 + b2 (4 tokens/block, bit-identical per-token
// fmaf chain) followed by in-block top-8 softmax + masked scatter.
// ---------------------------------------------------------------------------
template <typename HT>
__global__ __launch_bounds__(256) void gemm2_topk(const HT* __restrict__ h,
                                                  const float* __restrict__ W2,
                                                  const float* __restrict__ bias2,
                                                  const float* __restrict__ amask,
                                                  float* __restrict__ out, int T) {
    __shared__ float hs[4][HALF];          // 32 KB
    __shared__ float red[4][4][NE];        // [q][t][e], 4 KB
    const int tid = threadIdx.x;
    const size_t r0 = (size_t)blockIdx.x * 4;

    // stage 4 h rows (flat 8192 floats, coalesced)
    float* hsf = &hs[0][0];
    const HT* hr = h + r0 * HALF;
#pragma unroll
    for (int it = 0; it < 8; ++it) {
        const int i = tid * 4 + it * 1024;
        hsf[i + 0] = hload(hr + i + 0);
        hsf[i + 1] = hload(hr + i + 1);
        hsf[i + 2] = hload(hr + i + 2);
        hsf[i + 3] = hload(hr + i + 3);
    }
    __syncthreads();

    const int e = tid & 63, qq = tid >> 6;
    float s0 = 0.f, s1 = 0.f, s2 = 0.f, s3 = 0.f;
    const float* w = W2 + e;
    const int kbeg = qq * 512;
    for (int k4 = kbeg; k4 < kbeg + 512; k4 += 4) {
        float4 h0 = *(const float4*)&hs[0][k4];
        float4 h1 = *(const float4*)&hs[1][k4];
        float4 h2 = *(const float4*)&hs[2][k4];
        float4 h3 = *(const float4*)&hs[3][k4];
        float wv;
        wv = w[(size_t)(k4 + 0) * NE];
        s0 = fmaf(h0.x, wv, s0); s1 = fmaf(h1.x, wv, s1); s2 = fmaf(h2.x, wv, s2); s3 = fmaf(h3.x, wv, s3);
        wv = w[(size_t)(k4 + 1) * NE];
        s0 = fmaf(h0.y, wv, s0); s1 = fmaf(h1.y, wv, s1); s2 = fmaf(h2.y, wv, s2); s3 = fmaf(h3.y, wv, s3);
        wv = w[(size_t)(k4 + 2) * NE];
        s0 = fmaf(h0.z, wv, s0); s1 = fmaf(h1.z, wv, s1); s2 = fmaf(h2.z, wv, s2); s3 = fmaf(h3.z, wv, s3);
        wv = w[(size_t)(k4 + 3) * NE];
        s0 = fmaf(h0.w, wv, s0); s1 = fmaf(h1.w, wv, s1); s2 = fmaf(h2.w, wv, s2); s3 = fmaf(h3.w, wv, s3);
    }
    red[qq][0][e] = s0;
    red[qq][1][e] = s1;
    red[qq][2][e] = s2;
    red[qq][3][e] = s3;
    __syncthreads();

    // ---- per-wave token: final reduce (same add tree), top-8 softmax, mask
    const int wave = tid >> 6, lane = tid & 63;
    const size_t r = r0 + wave;
    const float v = ((red[0][wave][lane] + red[1][wave][lane]) +
                     (red[2][wave][lane] + red[3][wave][lane])) + bias2[lane];
    const float mk = amask[r];

    out[(size_t)T * NE + r * NE + lane] = v * mk;   // router_logits

    bool  sel = false;
    float m0 = 0.f, Z = 0.f;
#pragma unroll
    for (int it = 0; it < TOPK; ++it) {
        float cand = sel ? -INFINITY : v;
        int   idx  = lane;
#pragma unroll
        for (int off = 32; off; off >>= 1) {
            float ov = __shfl_xor(cand, off, 64);
            int   oi = __shfl_xor(idx,  off, 64);
            if (ov > cand || (ov == cand && oi < idx)) { cand = ov; idx = oi; }
        }
        if (it == 0) m0 = cand;
        Z += expf(cand - m0);
        if (lane == idx) sel = true;
    }
    const float wgt = sel ? (expf(v - m0) / Z) : 0.f;
    out[r * NE + lane] = wgt * mk;
}

// ---------------------------------------------------------------------------
// Fallback K1 (round-2): in-kernel conversion, fp32/bf16 h.
// ---------------------------------------------------------------------------
template <typename HT>
__global__ __launch_bounds__(256, 2) void gemm1_gelu_mfma(const float* __restrict__ x,
                                                          const float* __restrict__ W1,
                                                          const float* __restrict__ bias1,
                                                          HT* __restrict__ h) {
    __shared__ unsigned short Ah[128][40];
    __shared__ unsigned short Al[128][40];
    __shared__ unsigned short Bh[128][40];
    __shared__ unsigned short Bl[128][40];

    const int tid  = threadIdx.x;
    const int m0   = blockIdx.x * 128;
    const int n0   = blockIdx.y * 128;
    const int wave = tid >> 6, lane = tid & 63;
    const int wm   = (wave & 1) * 64;
    const int wn   = (wave >> 1) * 64;
    const int l15  = lane & 15;
    const int q    = lane >> 4;
    const int sm = tid & 127;
    const int kh = (tid >> 7) * 16;

    floatx4 acc[4][4];
#pragma unroll
    for (int i = 0; i < 4; ++i)
#pragma unroll
        for (int j = 0; j < 4; ++j) acc[i][j] = (floatx4)0.f;

    const float* xp = x  + (size_t)(m0 + sm) * HIDDEN + kh;
    const float* wp = W1 + (size_t)kh * HALF + n0 + sm;

    for (int k0 = 0; k0 < HIDDEN; k0 += 32) {
        float4 av[4];
#pragma unroll
        for (int i = 0; i < 4; ++i) av[i] = *(const float4*)(xp + k0 + i * 4);
        float bv[16];
#pragma unroll
        for (int i = 0; i < 16; ++i) bv[i] = wp[(size_t)(k0 + i) * HALF];

        __syncthreads();
        {
            unsigned short hi[16], lo[16];
#pragma unroll
            for (int i = 0; i < 4; ++i) {
                const float vs[4] = {av[i].x, av[i].y, av[i].z, av[i].w};
#pragma unroll
                for (int j = 0; j < 4; ++j) {
                    float v = vs[j];
                    unsigned short hb = bf16_rne(v);
                    hi[i * 4 + j] = hb;
                    lo[i * 4 + j] = bf16_rne(v - bf16_to_f(hb));
                }
            }
            *(short8*)&Ah[sm][kh]     = *(const short8*)&hi[0];
            *(short8*)&Ah[sm][kh + 8] = *(const short8*)&hi[8];
            *(short8*)&Al[sm][kh]     = *(const short8*)&lo[0];
            *(short8*)&Al[sm][kh + 8] = *(const short8*)&lo[8];
        }
        {
            unsigned short hi[16], lo[16];
#pragma unroll
            for (int i = 0; i < 16; ++i) {
                float v = bv[i];
                unsigned short hb = bf16_rne(v);
                hi[i] = hb;
                lo[i] = bf16_rne(v - bf16_to_f(hb));
            }
            *(short8*)&Bh[sm][kh]     = *(const short8*)&hi[0];
            *(short8*)&Bh[sm][kh + 8] = *(const short8*)&hi[8];
            *(short8*)&Bl[sm][kh]     = *(const short8*)&lo[0];
            *(short8*)&Bl[sm][kh + 8] = *(const short8*)&lo[8];
        }
        __syncthreads();

        short8 a_hi[4], a_lo[4], b_hi[4], b_lo[4];
#pragma unroll
        for (int t = 0; t < 4; ++t) {
            a_hi[t] = *(const short8*)&Ah[wm + t * 16 + l15][q * 8];
            a_lo[t] = *(const short8*)&Al[wm + t * 16 + l15][q * 8];
            b_hi[t] = *(const short8*)&Bh[wn + t * 16 + l15][q * 8];
            b_lo[t] = *(const short8*)&Bl[wn + t * 16 + l15][q * 8];
        }
#pragma unroll
        for (int i = 0; i < 4; ++i)
#pragma unroll
            for (int j = 0; j < 4; ++j) {
                acc[i][j] = __builtin_amdgcn_mfma_f32_16x16x32_bf16(a_hi[i], b_hi[j], acc[i][j], 0, 0, 0);
                acc[i][j] = __builtin_amdgcn_mfma_f32_16x16x32_bf16(a_lo[i], b_hi[j], acc[i][j], 0, 0, 0);
                acc[i][j] = __builtin_amdgcn_mfma_f32_16x16x32_bf16(a_hi[i], b_lo[j], acc[i][j], 0, 0, 0);
            }
    }

#pragma unroll
    for (int j = 0; j < 4; ++j) {
        const int n = n0 + wn + j * 16 + l15;
        const float bb = bias1[n];
#pragma unroll
        for (int i = 0; i < 4; ++i) {
            const int mbase = m0 + wm + i * 16 + q * 4;
#pragma unroll
            for (int r = 0; r < 4; ++r) {
                float v = acc[i][j][r] + bb;
                float g = 0.5f * v * (1.0f + erff(v * 0.70710678118654752f));
                hstore(h + (size_t)(mbase + r) * HALF + n, g);
            }
        }
    }
}

// ---------------------------------------------------------------------------
extern "C" void kernel_launch(void* const* d_in, const int* in_sizes, int n_in,
                              void* d_out, int out_size, void* d_ws, size_t ws_size,
                              hipStream_t stream) {
    const float* x   = (const float*)d_in[0];
    const float* am  = (const float*)d_in[1];
    const float* W1  = (const float*)d_in[2];
    const float* b1  = (const float*)d_in[3];
    const float* W2  = (const float*)d_in[4];
    const float* b2  = (const float*)d_in[5];
    float* out = (float*)d_out;

    const int T = in_sizes[0] / HIDDEN;   // 16384

    const size_t h32_bytes     = (size_t)T * HALF * sizeof(float);    // 134 MB
    const size_t xsplit_bytes  = (size_t)T * HIDDEN * 2;              // 134 MB each
    const size_t w1split_bytes = (size_t)HIDDEN * HALF * 2;           // 16.8 MB each
    const size_t need_new = h32_bytes + 2 * xsplit_bytes + 2 * w1split_bytes;

    if (ws_size >= need_new) {
        char* p = (char*)d_ws;
        float* h = (float*)p;                     p += h32_bytes;
        unsigned short* xhp = (unsigned short*)p; p += xsplit_bytes;
        unsigned short* xlp = (unsigned short*)p; p += xsplit_bytes;
        unsigned short* w1h = (unsigned short*)p; p += w1split_bytes;
        unsigned short* w1l = (unsigned short*)p;

        const size_t xN = (size_t)T * HIDDEN;
        hipLaunchKernelGGL(split_x_k, dim3(xN / (4 * 256)), dim3(256), 0, stream, x, xhp, xlp);
        hipLaunchKernelGGL(split_wt_k, dim3(HIDDEN / 64, HALF / 64), dim3(256), 0, stream,
                           W1, w1h, w1l, HIDDEN, HALF);
        hipLaunchKernelGGL(gemm1_gelu_pre, dim3((T / 256) * (HALF / 256)), dim3(512), 0, stream,
                           xhp, xlp, w1h, w1l, b1, h);
        hipLaunchKernelGGL((gemm2_topk<float>), dim3(T / 4), dim3(256), 0, stream,
                           h, W2, b2, am, out, T);
    } else if (ws_size >= h32_bytes) {
        float* h = (float*)d_ws;
        hipLaunchKernelGGL((gemm1_gelu_mfma<float>), dim3(T / 128, HALF / 128), dim3(256), 0, stream,
                           x, W1, b1, h);
        hipLaunchKernelGGL((gemm2_topk<float>), dim3(T / 4), dim3(256), 0, stream,
                           h, W2, b2, am, out, T);
    } else {
        __hip_bfloat16* h = (__hip_bfloat16*)d_ws;
        hipLaunchKernelGGL((gemm1_gelu_mfma<__hip_bfloat16>), dim3(T / 128, HALF / 128), dim3(256), 0, stream,
                           x, W1, b1, h);
        hipLaunchKernelGGL((gemm2_topk<__hip_bfloat16>), dim3(T / 4), dim3(256), 0, stream,
                           h, W2, b2, am, out, T);
    }
}